// Round 4
// baseline (564.853 us; speedup 1.0000x reference)
//
#include <hip/hip_runtime.h>
#include <math.h>

#define NEG_SLOPE 0.2f

typedef unsigned int uint;
typedef unsigned short ushort;

__device__ __forceinline__ uint bf16pack(float a, float b) {
    uint ua = __float_as_uint(a), ub = __float_as_uint(b);
    ua = (ua + 0x7fffu + ((ua >> 16) & 1u)) >> 16;
    ub = (ub + 0x7fffu + ((ub >> 16) & 1u)) >> 16;
    return ua | (ub << 16);
}

// ---------- tiny init ----------
__global__ void zero_counts_kernel(int* __restrict__ count, int* __restrict__ cursor, int N) {
    int i = blockIdx.x * blockDim.x + threadIdx.x;
    if (i < N) { count[i] = 0; cursor[i] = 0; }
}

__global__ void init_wsum_kernel(float* __restrict__ wsum) {
    if (threadIdx.x < 2) wsum[threadIdx.x] = 0.f;
}

// ---------- fc: feat = h@W + fused el/er ----------
// 64 nodes/block, 256 threads = 8 rowgroups(8 rows) x 32 colgroups(8 cols)
// per K-step: 8 broadcast LDS reads + 2 float4 W loads + 64 FMA
__global__ void __launch_bounds__(256, 4)
fc_kernel(const float* __restrict__ h, const float* __restrict__ W,
          const float* __restrict__ al, const float* __restrict__ ar,
          float* __restrict__ feat, float* __restrict__ el,
          float* __restrict__ er, int N) {
    __shared__ float hs[64][128];
    int n0 = blockIdx.x * 64;
    for (int t = threadIdx.x; t < 64 * 32; t += 256) {
        int r = t >> 5, i4 = t & 31;
        int n = n0 + r;
        float4 v = make_float4(0.f, 0.f, 0.f, 0.f);
        if (n < N) v = ((const float4*)h)[(size_t)n * 32 + i4];
        ((float4*)hs[r])[i4] = v;
    }
    __syncthreads();
    int cg = threadIdx.x & 31;
    int rg = threadIdx.x >> 5;
    float acc[8][8];
#pragma unroll
    for (int r = 0; r < 8; r++)
#pragma unroll
        for (int c = 0; c < 8; c++) acc[r][c] = 0.f;

    const float4* Wv = (const float4*)W;
#pragma unroll 2
    for (int i = 0; i < 128; i++) {
        float4 w0 = Wv[(size_t)i * 64 + cg * 2];
        float4 w1 = Wv[(size_t)i * 64 + cg * 2 + 1];
        float wv[8] = {w0.x, w0.y, w0.z, w0.w, w1.x, w1.y, w1.z, w1.w};
        float zv[8];
#pragma unroll
        for (int r = 0; r < 8; r++) zv[r] = hs[rg * 8 + r][i];
#pragma unroll
        for (int r = 0; r < 8; r++)
#pragma unroll
            for (int c = 0; c < 8; c++) acc[r][c] += zv[r] * wv[c];
    }

    float alv[8], arv[8];
    {
        float4 a0 = ((const float4*)al)[cg * 2], a1 = ((const float4*)al)[cg * 2 + 1];
        float4 b0 = ((const float4*)ar)[cg * 2], b1 = ((const float4*)ar)[cg * 2 + 1];
        alv[0]=a0.x; alv[1]=a0.y; alv[2]=a0.z; alv[3]=a0.w; alv[4]=a1.x; alv[5]=a1.y; alv[6]=a1.z; alv[7]=a1.w;
        arv[0]=b0.x; arv[1]=b0.y; arv[2]=b0.z; arv[3]=b0.w; arv[4]=b1.x; arv[5]=b1.y; arv[6]=b1.z; arv[7]=b1.w;
    }
    int hh = cg >> 2;
#pragma unroll
    for (int r = 0; r < 8; r++) {
        int n = n0 + rg * 8 + r;
        bool valid = (n < N);
        if (valid) {
            float4 f0 = make_float4(acc[r][0], acc[r][1], acc[r][2], acc[r][3]);
            float4 f1 = make_float4(acc[r][4], acc[r][5], acc[r][6], acc[r][7]);
            ((float4*)(feat + (size_t)n * 256))[cg * 2] = f0;
            ((float4*)(feat + (size_t)n * 256))[cg * 2 + 1] = f1;
        }
        float pl = 0.f, pr = 0.f;
#pragma unroll
        for (int c = 0; c < 8; c++) { pl += acc[r][c] * alv[c]; pr += acc[r][c] * arv[c]; }
        pl += __shfl_xor(pl, 1, 64); pr += __shfl_xor(pr, 1, 64);
        pl += __shfl_xor(pl, 2, 64); pr += __shfl_xor(pr, 2, 64);
        if ((cg & 3) == 0 && valid) {
            el[(size_t)n * 8 + hh] = pl;
            er[(size_t)n * 8 + hh] = pr;
        }
    }
}

// ---------- CSR build ----------
__global__ void hist_kernel(const int* __restrict__ edges, int* __restrict__ count, int E) {
    int e = blockIdx.x * blockDim.x + threadIdx.x;
    if (e < E) atomicAdd(&count[edges[E + e]], 1);
}

__global__ void scan1_kernel(const int* __restrict__ count, int* __restrict__ base,
                             int* __restrict__ bsum, int N) {
    __shared__ int wsum[4];
    int b = blockIdx.x;
    int i = b * 256 + threadIdx.x;
    int v = (i < N) ? count[i] : 0;
    int lane = threadIdx.x & 63;
    int wid = threadIdx.x >> 6;
    int x = v;
#pragma unroll
    for (int s = 1; s < 64; s <<= 1) {
        int y = __shfl_up(x, s, 64);
        if (lane >= s) x += y;
    }
    if (lane == 63) wsum[wid] = x;
    __syncthreads();
    int add = 0;
    for (int w = 0; w < wid; w++) add += wsum[w];
    int incl = x + add;
    if (i < N) base[i] = incl - v;
    if (threadIdx.x == 255) bsum[b] = incl;
}

__global__ void scan2_kernel(int* __restrict__ bsum, int nb) {
    __shared__ int wsum[4];
    int i = threadIdx.x;
    int v = (i < nb) ? bsum[i] : 0;
    int lane = threadIdx.x & 63;
    int wid = threadIdx.x >> 6;
    int x = v;
#pragma unroll
    for (int s = 1; s < 64; s <<= 1) {
        int y = __shfl_up(x, s, 64);
        if (lane >= s) x += y;
    }
    if (lane == 63) wsum[wid] = x;
    __syncthreads();
    int add = 0;
    for (int w = 0; w < wid; w++) add += wsum[w];
    if (i < nb) bsum[i] = x + add - v;
}

__global__ void scan3_kernel(int* __restrict__ base, const int* __restrict__ bsum, int N) {
    int i = blockIdx.x * blockDim.x + threadIdx.x;
    if (i < N) base[i] += bsum[i >> 8];
}

__global__ void scatter_kernel(const int* __restrict__ edges, const float* __restrict__ el,
                               const float* __restrict__ er, const int* __restrict__ base,
                               int* __restrict__ cursor, int* __restrict__ csr_src,
                               float* __restrict__ eedge, int E) {
    int e = blockIdx.x * blockDim.x + threadIdx.x;
    if (e >= E) return;
    int src = edges[e];
    int dst = edges[E + e];
    int pos = base[dst] + atomicAdd(&cursor[dst], 1);
    csr_src[pos] = src;
    float4 l0 = ((const float4*)el)[src * 2];
    float4 l1 = ((const float4*)el)[src * 2 + 1];
    float4 r0 = ((const float4*)er)[dst * 2];
    float4 r1 = ((const float4*)er)[dst * 2 + 1];
    float v[8] = {l0.x + r0.x, l0.y + r0.y, l0.z + r0.z, l0.w + r0.w,
                  l1.x + r1.x, l1.y + r1.y, l1.z + r1.z, l1.w + r1.w};
#pragma unroll
    for (int k = 0; k < 8; k++) v[k] = (v[k] > 0.f) ? v[k] : NEG_SLOPE * v[k];
    ((float4*)eedge)[pos * 2]     = make_float4(v[0], v[1], v[2], v[3]);
    ((float4*)eedge)[pos * 2 + 1] = make_float4(v[4], v[5], v[6], v[7]);
}

// ---------- aggregate: one wave per dst, online softmax ----------
__global__ void aggregate_csr_kernel(const int* __restrict__ csr_src, const float* __restrict__ eedge,
                                     const int* __restrict__ base, const int* __restrict__ count,
                                     const float* __restrict__ feat, const float* __restrict__ bias,
                                     float* __restrict__ z, int N) {
    int wid = threadIdx.x >> 6;
    int lane = threadIdx.x & 63;
    int dst = blockIdx.x * 4 + wid;
    if (dst >= N) return;
    int row0 = base[dst];
    int deg = count[dst];
    int h = lane >> 3;
    float m = -INFINITY;
    float denom = 0.f;
    float4 acc = make_float4(0.f, 0.f, 0.f, 0.f);
    for (int t = 0; t < deg; t++) {
        int pos = row0 + t;
        float e = eedge[(size_t)pos * 8 + h];
        int src = csr_src[pos];
        float4 f = ((const float4*)feat)[src * 64 + lane];
        float nm = fmaxf(m, e);
        float scale = __expf(m - nm);
        float p = __expf(e - nm);
        denom = denom * scale + p;
        acc.x = acc.x * scale + p * f.x;
        acc.y = acc.y * scale + p * f.y;
        acc.z = acc.z * scale + p * f.z;
        acc.w = acc.w * scale + p * f.w;
        m = nm;
    }
    float4 bz = ((const float4*)bias)[lane];
    float inv = (denom > 0.f) ? 1.f / denom : 0.f;
    float4 o = make_float4(acc.x * inv + bz.x, acc.y * inv + bz.y,
                           acc.z * inv + bz.z, acc.w * inv + bz.w);
    ((float4*)z)[dst * 64 + lane] = o;
}

// ---------- semantic attention ----------
// 32 nodes/block (64 rows = node*2+mm), bf16 z staged in LDS.
// 256 threads = 16 rowgroups(4 rows) x 16 colgroups(8 cols); K-chunked by 8.
#define ZROW 264   // 256 + 8 ushort pad (breaks same-bank broadcast)
__global__ void __launch_bounds__(256, 4)
semantic_kernel(const float* __restrict__ z0, const float* __restrict__ z1,
                const float* __restrict__ sw1, const float* __restrict__ sb1,
                const float* __restrict__ sw2, float* __restrict__ wsum, int N) {
    __shared__ ushort zs[64 * ZROW];      // ~33 KB
    __shared__ float sh_w[2];
    int n0 = blockIdx.x * 32;
    if (threadIdx.x < 2) sh_w[threadIdx.x] = 0.f;
    for (int t = threadIdx.x; t < 32 * 2 * 64; t += 256) {
        int r = t >> 7;                   // local node 0..31
        int rem = t & 127;
        int mm = rem >> 6;
        int i4 = rem & 63;                // float4 chunk
        int n = n0 + r;
        float4 v = make_float4(0.f, 0.f, 0.f, 0.f);
        if (n < N) v = ((const float4*)(mm ? z1 : z0))[(size_t)n * 64 + i4];
        uint2 p;
        p.x = bf16pack(v.x, v.y);
        p.y = bf16pack(v.z, v.w);
        *((uint2*)(zs + (r * 2 + mm) * ZROW + i4 * 4)) = p;
    }
    __syncthreads();

    int cg = threadIdx.x & 15;            // 8 cols each
    int rg = threadIdx.x >> 4;            // 4 rows each

    float acc[4][8];
    {
        float4 s0 = ((const float4*)sb1)[cg * 2], s1 = ((const float4*)sb1)[cg * 2 + 1];
        float sbv[8] = {s0.x, s0.y, s0.z, s0.w, s1.x, s1.y, s1.z, s1.w};
#pragma unroll
        for (int r = 0; r < 4; r++)
#pragma unroll
            for (int c = 0; c < 8; c++) acc[r][c] = sbv[c];
    }

    for (int i0 = 0; i0 < 256; i0 += 8) {
        uint4 zr[4];
#pragma unroll
        for (int r = 0; r < 4; r++)
            zr[r] = *((const uint4*)(zs + (rg * 4 + r) * ZROW + i0));
#pragma unroll
        for (int k = 0; k < 8; k++) {
            const float4* wrow = (const float4*)(sw1 + (size_t)(i0 + k) * 128);
            float4 w0 = wrow[cg * 2];
            float4 w1 = wrow[cg * 2 + 1];
            float wv[8] = {w0.x, w0.y, w0.z, w0.w, w1.x, w1.y, w1.z, w1.w};
            float zv[4];
#pragma unroll
            for (int r = 0; r < 4; r++) {
                uint u = ((const uint*)&zr[r])[k >> 1];
                zv[r] = __uint_as_float((k & 1) ? (u & 0xffff0000u) : (u << 16));
            }
#pragma unroll
            for (int r = 0; r < 4; r++)
#pragma unroll
                for (int c = 0; c < 8; c++) acc[r][c] += zv[r] * wv[c];
        }
    }

    float s2v[8];
    {
        float4 s0 = ((const float4*)sw2)[cg * 2], s1 = ((const float4*)sw2)[cg * 2 + 1];
        s2v[0]=s0.x; s2v[1]=s0.y; s2v[2]=s0.z; s2v[3]=s0.w; s2v[4]=s1.x; s2v[5]=s1.y; s2v[6]=s1.z; s2v[7]=s1.w;
    }
    float wpair[2] = {0.f, 0.f};
#pragma unroll
    for (int r = 0; r < 4; r++) {
        int row = rg * 4 + r;
        int node = n0 + (row >> 1);
        float p = 0.f;
#pragma unroll
        for (int c = 0; c < 8; c++) p += tanhf(acc[r][c]) * s2v[c];
        if (node < N) wpair[row & 1] += p;
    }
#pragma unroll
    for (int s = 1; s <= 32; s <<= 1) {
        wpair[0] += __shfl_xor(wpair[0], s, 64);
        wpair[1] += __shfl_xor(wpair[1], s, 64);
    }
    if ((threadIdx.x & 63) == 0) {
        atomicAdd(&sh_w[0], wpair[0]);
        atomicAdd(&sh_w[1], wpair[1]);
    }
    __syncthreads();
    if (threadIdx.x < 2) atomicAdd(&wsum[threadIdx.x], sh_w[threadIdx.x]);
}

// ---------- beta = softmax(wsum/N) ----------
__global__ void beta_kernel(const float* __restrict__ wsum, float* __restrict__ beta, float invN) {
    if (threadIdx.x == 0 && blockIdx.x == 0) {
        float w0 = wsum[0] * invN, w1 = wsum[1] * invN;
        float mx = fmaxf(w0, w1);
        float e0 = expf(w0 - mx), e1 = expf(w1 - mx);
        float s = e0 + e1;
        beta[0] = e0 / s;
        beta[1] = e1 / s;
    }
}

// ---------- out = beta0*z0 + beta1*z1 ----------
__global__ void combine_kernel(float* __restrict__ out, const float* __restrict__ z1,
                               const float* __restrict__ beta, int total4) {
    int idx = blockIdx.x * blockDim.x + threadIdx.x;
    if (idx >= total4) return;
    float b0 = beta[0], b1 = beta[1];
    float4 a = ((const float4*)out)[idx];
    float4 b = ((const float4*)z1)[idx];
    float4 r;
    r.x = b0 * a.x + b1 * b.x;
    r.y = b0 * a.y + b1 * b.y;
    r.z = b0 * a.z + b1 * b.z;
    r.w = b0 * a.w + b1 * b.w;
    ((float4*)out)[idx] = r;
}

extern "C" void kernel_launch(void* const* d_in, const int* in_sizes, int n_in,
                              void* d_out, int out_size, void* d_ws, size_t ws_size,
                              hipStream_t stream) {
    const float* h      = (const float*)d_in[0];
    const int*   edges0 = (const int*)d_in[1];
    const int*   edges1 = (const int*)d_in[2];
    const float* fc0    = (const float*)d_in[3];
    const float* al0    = (const float*)d_in[4];
    const float* ar0    = (const float*)d_in[5];
    const float* bias0  = (const float*)d_in[6];
    const float* fc1    = (const float*)d_in[7];
    const float* al1    = (const float*)d_in[8];
    const float* ar1    = (const float*)d_in[9];
    const float* bias1  = (const float*)d_in[10];
    const float* sw1    = (const float*)d_in[11];
    const float* sb1    = (const float*)d_in[12];
    const float* sw2    = (const float*)d_in[13];

    const int N = in_sizes[0] / 128;
    const int E = in_sizes[1] / 2;
    const int NB = (N + 255) / 256;

    float* ws    = (float*)d_ws;
    float* feat  = ws;                          // N*256
    float* z1    = feat + (size_t)N * 256;      // N*256
    float* el    = z1 + (size_t)N * 256;        // N*8
    float* er    = el + (size_t)N * 8;          // N*8
    float* eedge = er + (size_t)N * 8;          // E*8
    float* fend  = eedge + (size_t)E * 8;
    int*   csr_src = (int*)fend;                // E
    int*   count   = csr_src + E;               // N
    int*   base    = count + N;                 // N
    int*   cursor  = base + N;                  // N
    int*   bsum    = cursor + N;                // NB
    float* wsum  = (float*)(bsum + NB + 2);     // 2
    float* beta  = wsum + 2;                    // 2
    float* z0    = (float*)d_out;               // N*256

    for (int l = 0; l < 2; l++) {
        const float* W    = l ? fc1 : fc0;
        const float* alp  = l ? al1 : al0;
        const float* arp  = l ? ar1 : ar0;
        const float* bias = l ? bias1 : bias0;
        const int*  edges = l ? edges1 : edges0;
        float* z = l ? z1 : z0;

        zero_counts_kernel<<<NB, 256, 0, stream>>>(count, cursor, N);
        fc_kernel<<<(N + 63) / 64, 256, 0, stream>>>(h, W, alp, arp, feat, el, er, N);
        hist_kernel<<<(E + 255) / 256, 256, 0, stream>>>(edges, count, E);
        scan1_kernel<<<NB, 256, 0, stream>>>(count, base, bsum, N);
        scan2_kernel<<<1, 256, 0, stream>>>(bsum, NB);
        scan3_kernel<<<NB, 256, 0, stream>>>(base, bsum, N);
        scatter_kernel<<<(E + 255) / 256, 256, 0, stream>>>(edges, el, er, base, cursor,
                                                            csr_src, eedge, E);
        aggregate_csr_kernel<<<(N + 3) / 4, 256, 0, stream>>>(csr_src, eedge, base, count,
                                                              feat, bias, z, N);
    }

    init_wsum_kernel<<<1, 64, 0, stream>>>(wsum);
    semantic_kernel<<<(N + 31) / 32, 256, 0, stream>>>(z0, z1, sw1, sb1, sw2, wsum, N);
    beta_kernel<<<1, 64, 0, stream>>>(wsum, beta, 1.0f / (float)N);
    combine_kernel<<<(N * 256 / 4 + 255) / 256, 256, 0, stream>>>(z0, z1, beta, N * 256 / 4);
}

// Round 5
// 408.413 us; speedup vs baseline: 1.3830x; 1.3830x over previous
//
#include <hip/hip_runtime.h>
#include <math.h>

#define NEG_SLOPE 0.2f

typedef unsigned int uint;
typedef unsigned short ushort;
typedef __bf16 bf16x8 __attribute__((ext_vector_type(8)));
typedef float f32x4 __attribute__((ext_vector_type(4)));

__device__ __forceinline__ uint bf16r(float a) {
    uint u = __float_as_uint(a);
    return (u + 0x7fffu + ((u >> 16) & 1u)) >> 16;
}
__device__ __forceinline__ uint bf16pack(float a, float b) {
    return bf16r(a) | (bf16r(b) << 16);
}
__device__ __forceinline__ float bflo(uint u) { return __uint_as_float(u << 16); }
__device__ __forceinline__ float bfhi(uint u) { return __uint_as_float(u & 0xffff0000u); }

// ---------- tiny init ----------
__global__ void zero_counts_kernel(int* __restrict__ count, int* __restrict__ cursor, int N) {
    int i = blockIdx.x * blockDim.x + threadIdx.x;
    if (i < N) { count[i] = 0; cursor[i] = 0; }
}

__global__ void init_wsum_kernel(float* __restrict__ wsum) {
    if (threadIdx.x < 2) wsum[threadIdx.x] = 0.f;
}

// ---------- sw1 -> bf16 transposed [128 cols][256 k] ----------
__global__ void sw1t_kernel(const float* __restrict__ sw1, ushort* __restrict__ sw1t) {
    int idx = blockIdx.x * 256 + threadIdx.x;   // 32768
    int k = idx >> 7, c = idx & 127;
    sw1t[(size_t)c * 256 + k] = (ushort)bf16r(sw1[idx]);
}

// ---------- fc: feat(bf16) = h@W + fused el/er (round-3 structure) ----------
// 32 nodes/block, 256 threads = 8 rowgroups(4 rows) x 32 colgroups(8 cols)
__global__ void fc_kernel(const float* __restrict__ h, const float* __restrict__ W,
                          const float* __restrict__ al, const float* __restrict__ ar,
                          ushort* __restrict__ featb, float* __restrict__ el,
                          float* __restrict__ er, int N) {
    __shared__ float hs[32][128];
    int n0 = blockIdx.x * 32;
    for (int t = threadIdx.x; t < 32 * 32; t += 256) {
        int r = t >> 5, i4 = t & 31;
        int n = n0 + r;
        float4 v = make_float4(0.f, 0.f, 0.f, 0.f);
        if (n < N) v = ((const float4*)h)[(size_t)n * 32 + i4];
        ((float4*)hs[r])[i4] = v;
    }
    __syncthreads();
    int cg = threadIdx.x & 31;
    int ng = threadIdx.x >> 5;
    float acc[4][8];
#pragma unroll
    for (int r = 0; r < 4; r++)
#pragma unroll
        for (int c = 0; c < 8; c++) acc[r][c] = 0.f;

    const float4* Wv = (const float4*)W;
#pragma unroll 4
    for (int i = 0; i < 128; i++) {
        float4 w0 = Wv[(size_t)i * 64 + cg * 2];
        float4 w1 = Wv[(size_t)i * 64 + cg * 2 + 1];
        float wv[8] = {w0.x, w0.y, w0.z, w0.w, w1.x, w1.y, w1.z, w1.w};
        float zv[4];
#pragma unroll
        for (int r = 0; r < 4; r++) zv[r] = hs[ng * 4 + r][i];
#pragma unroll
        for (int r = 0; r < 4; r++)
#pragma unroll
            for (int c = 0; c < 8; c++) acc[r][c] += zv[r] * wv[c];
    }

    float alv[8], arv[8];
    {
        float4 a0 = ((const float4*)al)[cg * 2], a1 = ((const float4*)al)[cg * 2 + 1];
        float4 b0 = ((const float4*)ar)[cg * 2], b1 = ((const float4*)ar)[cg * 2 + 1];
        alv[0]=a0.x; alv[1]=a0.y; alv[2]=a0.z; alv[3]=a0.w; alv[4]=a1.x; alv[5]=a1.y; alv[6]=a1.z; alv[7]=a1.w;
        arv[0]=b0.x; arv[1]=b0.y; arv[2]=b0.z; arv[3]=b0.w; arv[4]=b1.x; arv[5]=b1.y; arv[6]=b1.z; arv[7]=b1.w;
    }
    int hh = cg >> 2;
#pragma unroll
    for (int r = 0; r < 4; r++) {
        int n = n0 + ng * 4 + r;
        bool valid = (n < N);
        if (valid) {
            uint4 pv;
            pv.x = bf16pack(acc[r][0], acc[r][1]);
            pv.y = bf16pack(acc[r][2], acc[r][3]);
            pv.z = bf16pack(acc[r][4], acc[r][5]);
            pv.w = bf16pack(acc[r][6], acc[r][7]);
            ((uint4*)(featb + (size_t)n * 256))[cg] = pv;
        }
        float pl = 0.f, pr = 0.f;
#pragma unroll
        for (int c = 0; c < 8; c++) { pl += acc[r][c] * alv[c]; pr += acc[r][c] * arv[c]; }
        pl += __shfl_xor(pl, 1, 64); pr += __shfl_xor(pr, 1, 64);
        pl += __shfl_xor(pl, 2, 64); pr += __shfl_xor(pr, 2, 64);
        if ((cg & 3) == 0 && valid) {
            el[(size_t)n * 8 + hh] = pl;
            er[(size_t)n * 8 + hh] = pr;
        }
    }
}

// ---------- CSR build ----------
__global__ void hist_kernel(const int* __restrict__ edges, int* __restrict__ count, int E) {
    int e = blockIdx.x * blockDim.x + threadIdx.x;
    if (e < E) atomicAdd(&count[edges[E + e]], 1);
}

__global__ void scan1_kernel(const int* __restrict__ count, int* __restrict__ base,
                             int* __restrict__ bsum, int N) {
    __shared__ int wsum[4];
    int b = blockIdx.x;
    int i = b * 256 + threadIdx.x;
    int v = (i < N) ? count[i] : 0;
    int lane = threadIdx.x & 63;
    int wid = threadIdx.x >> 6;
    int x = v;
#pragma unroll
    for (int s = 1; s < 64; s <<= 1) {
        int y = __shfl_up(x, s, 64);
        if (lane >= s) x += y;
    }
    if (lane == 63) wsum[wid] = x;
    __syncthreads();
    int add = 0;
    for (int w = 0; w < wid; w++) add += wsum[w];
    int incl = x + add;
    if (i < N) base[i] = incl - v;
    if (threadIdx.x == 255) bsum[b] = incl;
}

__global__ void scan2_kernel(int* __restrict__ bsum, int nb) {
    __shared__ int wsum[4];
    int i = threadIdx.x;
    int v = (i < nb) ? bsum[i] : 0;
    int lane = threadIdx.x & 63;
    int wid = threadIdx.x >> 6;
    int x = v;
#pragma unroll
    for (int s = 1; s < 64; s <<= 1) {
        int y = __shfl_up(x, s, 64);
        if (lane >= s) x += y;
    }
    if (lane == 63) wsum[wid] = x;
    __syncthreads();
    int add = 0;
    for (int w = 0; w < wid; w++) add += wsum[w];
    if (i < nb) bsum[i] = x + add - v;
}

__global__ void scan3_kernel(int* __restrict__ base, const int* __restrict__ bsum, int N) {
    int i = blockIdx.x * blockDim.x + threadIdx.x;
    if (i < N) base[i] += bsum[i >> 8];
}

__global__ void scatter_kernel(const int* __restrict__ edges, const float* __restrict__ el,
                               const float* __restrict__ er, const int* __restrict__ base,
                               int* __restrict__ cursor, int* __restrict__ csr_src,
                               float* __restrict__ eedge, int E) {
    int e = blockIdx.x * blockDim.x + threadIdx.x;
    if (e >= E) return;
    int src = edges[e];
    int dst = edges[E + e];
    int pos = base[dst] + atomicAdd(&cursor[dst], 1);
    csr_src[pos] = src;
    float4 l0 = ((const float4*)el)[src * 2];
    float4 l1 = ((const float4*)el)[src * 2 + 1];
    float4 r0 = ((const float4*)er)[dst * 2];
    float4 r1 = ((const float4*)er)[dst * 2 + 1];
    float v[8] = {l0.x + r0.x, l0.y + r0.y, l0.z + r0.z, l0.w + r0.w,
                  l1.x + r1.x, l1.y + r1.y, l1.z + r1.z, l1.w + r1.w};
#pragma unroll
    for (int k = 0; k < 8; k++) v[k] = (v[k] > 0.f) ? v[k] : NEG_SLOPE * v[k];
    ((float4*)eedge)[pos * 2]     = make_float4(v[0], v[1], v[2], v[3]);
    ((float4*)eedge)[pos * 2 + 1] = make_float4(v[4], v[5], v[6], v[7]);
}

// ---------- aggregate: one wave per dst, dual-stream online softmax, bf16 feat ----------
__global__ void aggregate_csr_kernel(const int* __restrict__ csr_src, const float* __restrict__ eedge,
                                     const int* __restrict__ base, const int* __restrict__ count,
                                     const ushort* __restrict__ featb, const float* __restrict__ bias,
                                     ushort* __restrict__ zb, int N) {
    int wid = threadIdx.x >> 6;
    int lane = threadIdx.x & 63;
    int dst = blockIdx.x * 4 + wid;
    if (dst >= N) return;
    int row0 = base[dst];
    int deg = count[dst];
    int h = lane >> 3;
    float mA = -INFINITY, dA = 0.f;
    float4 aA = make_float4(0.f, 0.f, 0.f, 0.f);
    float mB = -INFINITY, dB = 0.f;
    float4 aB = make_float4(0.f, 0.f, 0.f, 0.f);
    int t = 0;
    for (; t + 1 < deg; t += 2) {
        int pA = row0 + t, pB = row0 + t + 1;
        float eA = eedge[(size_t)pA * 8 + h];
        float eB = eedge[(size_t)pB * 8 + h];
        int sA = csr_src[pA], sB = csr_src[pB];
        uint2 uA = ((const uint2*)featb)[(size_t)sA * 64 + lane];
        uint2 uB = ((const uint2*)featb)[(size_t)sB * 64 + lane];
        float nmA = fmaxf(mA, eA);
        float sclA = __expf(mA - nmA), pAv = __expf(eA - nmA);
        dA = dA * sclA + pAv;
        aA.x = aA.x * sclA + pAv * bflo(uA.x);
        aA.y = aA.y * sclA + pAv * bfhi(uA.x);
        aA.z = aA.z * sclA + pAv * bflo(uA.y);
        aA.w = aA.w * sclA + pAv * bfhi(uA.y);
        mA = nmA;
        float nmB = fmaxf(mB, eB);
        float sclB = __expf(mB - nmB), pBv = __expf(eB - nmB);
        dB = dB * sclB + pBv;
        aB.x = aB.x * sclB + pBv * bflo(uB.x);
        aB.y = aB.y * sclB + pBv * bfhi(uB.x);
        aB.z = aB.z * sclB + pBv * bflo(uB.y);
        aB.w = aB.w * sclB + pBv * bfhi(uB.y);
        mB = nmB;
    }
    if (t < deg) {
        int pA = row0 + t;
        float eA = eedge[(size_t)pA * 8 + h];
        int sA = csr_src[pA];
        uint2 uA = ((const uint2*)featb)[(size_t)sA * 64 + lane];
        float nmA = fmaxf(mA, eA);
        float sclA = __expf(mA - nmA), pAv = __expf(eA - nmA);
        dA = dA * sclA + pAv;
        aA.x = aA.x * sclA + pAv * bflo(uA.x);
        aA.y = aA.y * sclA + pAv * bfhi(uA.x);
        aA.z = aA.z * sclA + pAv * bflo(uA.y);
        aA.w = aA.w * sclA + pAv * bfhi(uA.y);
        mA = nmA;
    }
    float m = fmaxf(mA, mB);
    float sa = (dA > 0.f) ? __expf(mA - m) : 0.f;
    float sb = (dB > 0.f) ? __expf(mB - m) : 0.f;
    float denom = dA * sa + dB * sb;
    float inv = (denom > 0.f) ? 1.f / denom : 0.f;
    float4 bz = ((const float4*)bias)[lane];
    float o0 = (aA.x * sa + aB.x * sb) * inv + bz.x;
    float o1 = (aA.y * sa + aB.y * sb) * inv + bz.y;
    float o2 = (aA.z * sa + aB.z * sb) * inv + bz.z;
    float o3 = (aA.w * sa + aB.w * sb) * inv + bz.w;
    uint2 outp;
    outp.x = bf16pack(o0, o1);
    outp.y = bf16pack(o2, o3);
    ((uint2*)zb)[(size_t)dst * 64 + lane] = outp;
}

// ---------- semantic attention via MFMA ----------
// 32 nodes/block (64 rows = node*2+mm), 256 threads = 4 waves.
// Wave w: rows w*16..w*16+15, all 128 cols; K=256 in 8 MFMA steps.
#define ZROW 264
__global__ void __launch_bounds__(256, 4)
semantic_kernel(const ushort* __restrict__ z0b, const ushort* __restrict__ z1b,
                const ushort* __restrict__ sw1t, const float* __restrict__ sb1,
                const float* __restrict__ sw2, float* __restrict__ wsum, int N) {
    __shared__ ushort zs[64 * ZROW];      // ~33 KB
    __shared__ float sh_w[2];
    int n0 = blockIdx.x * 32;
    if (threadIdx.x < 2) sh_w[threadIdx.x] = 0.f;
    for (int t = threadIdx.x; t < 64 * 32; t += 256) {
        int row = t >> 5, i16 = t & 31;
        int r = row >> 1, mm = row & 1;
        int n = n0 + r;
        uint4 v = make_uint4(0u, 0u, 0u, 0u);
        if (n < N) v = ((const uint4*)(mm ? z1b : z0b))[(size_t)n * 32 + i16];
        *((uint4*)(zs + row * ZROW + i16 * 8)) = v;
    }
    __syncthreads();

    int wave = threadIdx.x >> 6;
    int lane = threadIdx.x & 63;
    int lhi = lane >> 4;          // 0..3
    int llo = lane & 15;          // 0..15
    int rowbase = wave * 16;

    f32x4 acc[8];
#pragma unroll
    for (int cb = 0; cb < 8; cb++) acc[cb] = (f32x4){0.f, 0.f, 0.f, 0.f};

    const ushort* arow = zs + (rowbase + llo) * ZROW + lhi * 8;
#pragma unroll
    for (int ks = 0; ks < 8; ks++) {
        bf16x8 a = *(const bf16x8*)(arow + ks * 32);
#pragma unroll
        for (int cb = 0; cb < 8; cb++) {
            bf16x8 b = *(const bf16x8*)(sw1t + (size_t)(cb * 16 + llo) * 256 + ks * 32 + lhi * 8);
            acc[cb] = __builtin_amdgcn_mfma_f32_16x16x32_bf16(a, b, acc[cb], 0, 0, 0);
        }
    }

    // epilogue: w += tanh(D + sb1[col]) * sw2[col]; D[row=(lane>>4)*4+reg][col=cb*16+llo]
    float part[4] = {0.f, 0.f, 0.f, 0.f};
#pragma unroll
    for (int cb = 0; cb < 8; cb++) {
        int col = cb * 16 + llo;
        float sb = sb1[col], s2 = sw2[col];
#pragma unroll
        for (int reg = 0; reg < 4; reg++)
            part[reg] += tanhf(acc[cb][reg] + sb) * s2;
    }
#pragma unroll
    for (int s = 1; s <= 8; s <<= 1) {
#pragma unroll
        for (int reg = 0; reg < 4; reg++) part[reg] += __shfl_xor(part[reg], s, 64);
    }
    if (llo == 0) {
        float w0 = 0.f, w1 = 0.f;
#pragma unroll
        for (int reg = 0; reg < 4; reg++) {
            int row = rowbase + lhi * 4 + reg;
            int node = n0 + (row >> 1);
            if (node < N) { if (row & 1) w1 += part[reg]; else w0 += part[reg]; }
        }
        atomicAdd(&sh_w[0], w0);
        atomicAdd(&sh_w[1], w1);
    }
    __syncthreads();
    if (threadIdx.x < 2) atomicAdd(&wsum[threadIdx.x], sh_w[threadIdx.x]);
}

// ---------- beta = softmax(wsum/N) ----------
__global__ void beta_kernel(const float* __restrict__ wsum, float* __restrict__ beta, float invN) {
    if (threadIdx.x == 0 && blockIdx.x == 0) {
        float w0 = wsum[0] * invN, w1 = wsum[1] * invN;
        float mx = fmaxf(w0, w1);
        float e0 = expf(w0 - mx), e1 = expf(w1 - mx);
        float s = e0 + e1;
        beta[0] = e0 / s;
        beta[1] = e1 / s;
    }
}

// ---------- out(f32) = beta0*z0b + beta1*z1b ----------
__global__ void combine_kernel(float* __restrict__ out, const ushort* __restrict__ z0b,
                               const ushort* __restrict__ z1b, const float* __restrict__ beta,
                               int total4) {
    int idx = blockIdx.x * blockDim.x + threadIdx.x;
    if (idx >= total4) return;
    float b0 = beta[0], b1 = beta[1];
    uint2 a = ((const uint2*)z0b)[idx];
    uint2 b = ((const uint2*)z1b)[idx];
    float4 r;
    r.x = b0 * bflo(a.x) + b1 * bflo(b.x);
    r.y = b0 * bfhi(a.x) + b1 * bfhi(b.x);
    r.z = b0 * bflo(a.y) + b1 * bflo(b.y);
    r.w = b0 * bfhi(a.y) + b1 * bfhi(b.y);
    ((float4*)out)[idx] = r;
}

extern "C" void kernel_launch(void* const* d_in, const int* in_sizes, int n_in,
                              void* d_out, int out_size, void* d_ws, size_t ws_size,
                              hipStream_t stream) {
    const float* h      = (const float*)d_in[0];
    const int*   edges0 = (const int*)d_in[1];
    const int*   edges1 = (const int*)d_in[2];
    const float* fc0    = (const float*)d_in[3];
    const float* al0    = (const float*)d_in[4];
    const float* ar0    = (const float*)d_in[5];
    const float* bias0  = (const float*)d_in[6];
    const float* fc1    = (const float*)d_in[7];
    const float* al1    = (const float*)d_in[8];
    const float* ar1    = (const float*)d_in[9];
    const float* bias1  = (const float*)d_in[10];
    const float* sw1    = (const float*)d_in[11];
    const float* sb1    = (const float*)d_in[12];
    const float* sw2    = (const float*)d_in[13];

    const int N = in_sizes[0] / 128;
    const int E = in_sizes[1] / 2;
    const int NB = (N + 255) / 256;

    char* ws = (char*)d_ws;
    ushort* featb = (ushort*)ws;                       // N*256 bf16
    ushort* z0b   = featb + (size_t)N * 256;           // N*256 bf16
    ushort* z1b   = z0b + (size_t)N * 256;             // N*256 bf16
    ushort* sw1t  = z1b + (size_t)N * 256;             // 128*256 bf16
    float*  el    = (float*)(sw1t + 128 * 256);        // N*8
    float*  er    = el + (size_t)N * 8;                // N*8
    float*  eedge = er + (size_t)N * 8;                // E*8
    int*    csr_src = (int*)(eedge + (size_t)E * 8);   // E
    int*    count   = csr_src + E;                     // N
    int*    base    = count + N;                       // N
    int*    cursor  = base + N;                        // N
    int*    bsum    = cursor + N;                      // NB
    float*  wsum  = (float*)(bsum + NB + 2);           // 2
    float*  beta  = wsum + 2;                          // 2
    float*  outp  = (float*)d_out;                     // N*256 f32

    sw1t_kernel<<<128, 256, 0, stream>>>(sw1, sw1t);

    for (int l = 0; l < 2; l++) {
        const float* W    = l ? fc1 : fc0;
        const float* alp  = l ? al1 : al0;
        const float* arp  = l ? ar1 : ar0;
        const float* bias = l ? bias1 : bias0;
        const int*  edges = l ? edges1 : edges0;
        ushort* zb = l ? z1b : z0b;

        zero_counts_kernel<<<NB, 256, 0, stream>>>(count, cursor, N);
        fc_kernel<<<(N + 31) / 32, 256, 0, stream>>>(h, W, alp, arp, featb, el, er, N);
        hist_kernel<<<(E + 255) / 256, 256, 0, stream>>>(edges, count, E);
        scan1_kernel<<<NB, 256, 0, stream>>>(count, base, bsum, N);
        scan2_kernel<<<1, 256, 0, stream>>>(bsum, NB);
        scan3_kernel<<<NB, 256, 0, stream>>>(base, bsum, N);
        scatter_kernel<<<(E + 255) / 256, 256, 0, stream>>>(edges, el, er, base, cursor,
                                                            csr_src, eedge, E);
        aggregate_csr_kernel<<<(N + 3) / 4, 256, 0, stream>>>(csr_src, eedge, base, count,
                                                              featb, bias, zb, N);
    }

    init_wsum_kernel<<<1, 64, 0, stream>>>(wsum);
    semantic_kernel<<<(N + 31) / 32, 256, 0, stream>>>(z0b, z1b, sw1t, sb1, sw2, wsum, N);
    beta_kernel<<<1, 64, 0, stream>>>(wsum, beta, 1.0f / (float)N);
    combine_kernel<<<(N * 256 / 4 + 255) / 256, 256, 0, stream>>>(outp, z0b, z1b, beta, N * 256 / 4);
}

// Round 6
// 338.874 us; speedup vs baseline: 1.6669x; 1.2052x over previous
//
#include <hip/hip_runtime.h>
#include <math.h>

#define NEG_SLOPE 0.2f

typedef unsigned int uint;
typedef unsigned short ushort;
typedef __bf16 bf16x8 __attribute__((ext_vector_type(8)));
typedef float f32x4 __attribute__((ext_vector_type(4)));

__device__ __forceinline__ uint bf16r(float a) {
    uint u = __float_as_uint(a);
    return (u + 0x7fffu + ((u >> 16) & 1u)) >> 16;
}
__device__ __forceinline__ uint bf16pack(float a, float b) {
    return bf16r(a) | (bf16r(b) << 16);
}
__device__ __forceinline__ float bflo(uint u) { return __uint_as_float(u << 16); }
__device__ __forceinline__ float bfhi(uint u) { return __uint_as_float(u & 0xffff0000u); }

// ---------- h -> bf16 (+ zero wsum) ----------
__global__ void hb_kernel(const float* __restrict__ h, ushort* __restrict__ hb,
                          float* __restrict__ wsum, int total8) {
    int i = blockIdx.x * 256 + threadIdx.x;
    if (i == 0) { wsum[0] = 0.f; wsum[1] = 0.f; }
    if (i >= total8) return;
    float4 v0 = ((const float4*)h)[(size_t)i * 2];
    float4 v1 = ((const float4*)h)[(size_t)i * 2 + 1];
    uint4 o;
    o.x = bf16pack(v0.x, v0.y);
    o.y = bf16pack(v0.z, v0.w);
    o.z = bf16pack(v1.x, v1.y);
    o.w = bf16pack(v1.z, v1.w);
    ((uint4*)hb)[i] = o;
}

// ---------- W(0/1) -> bf16 transposed [col 256][k 128] ----------
__global__ void wbt_kernel(const float* __restrict__ W0, const float* __restrict__ W1,
                           ushort* __restrict__ wbt) {
    int idx = blockIdx.x * 256 + threadIdx.x;   // 65536
    const float* W = (idx >> 15) ? W1 : W0;
    int r = idx & 32767;
    int c = r >> 7, k = r & 127;
    wbt[idx] = (ushort)bf16r(W[(size_t)k * 256 + c]);
}

// ---------- sw1 -> bf16 [c 128][k'=p 256] with z's permuted k layout ----------
__global__ void sw1t_kernel(const float* __restrict__ sw1, ushort* __restrict__ sw1t) {
    int idx = blockIdx.x * 256 + threadIdx.x;   // 32768
    int c = idx >> 8, p = idx & 255;
    int col = (p & ~63) + ((p & 3) * 16) + ((p >> 2) & 15);
    sw1t[idx] = (ushort)bf16r(sw1[(size_t)col * 128 + c]);
}

__global__ void zero_counts_kernel(int* __restrict__ count, int* __restrict__ cursor, int N) {
    int i = blockIdx.x * blockDim.x + threadIdx.x;
    if (i < N) { count[i] = 0; cursor[i] = 0; }
}

// ---------- fc via MFMA: featb(perm bf16) = hb@W + fused el/er ----------
// 64 nodes/block, 4 waves. Wave w: cols 64w..64w+63 (4 col-tiles), all 64 rows.
// feat layout: featb[n*256 + p], p = 64w + 4*llo + cb  (col = 64w + 16cb + llo)
#define HKPAD 136
__global__ void __launch_bounds__(256, 4)
fc_kernel(const ushort* __restrict__ hb, const ushort* __restrict__ wbt,
          const float* __restrict__ al, const float* __restrict__ ar,
          ushort* __restrict__ featb, float* __restrict__ el,
          float* __restrict__ er, int N) {
    __shared__ ushort hs[64 * HKPAD];
    int n0 = blockIdx.x * 64;
    for (int t = threadIdx.x; t < 64 * 16; t += 256) {
        int r = t >> 4, i8 = t & 15;
        int n = n0 + r;
        uint4 v = make_uint4(0u, 0u, 0u, 0u);
        if (n < N) v = ((const uint4*)hb)[(size_t)n * 16 + i8];
        *((uint4*)(hs + r * HKPAD + i8 * 8)) = v;
    }
    __syncthreads();

    int wv = threadIdx.x >> 6;
    int lane = threadIdx.x & 63;
    int lhi = lane >> 4, llo = lane & 15;

    f32x4 acc[4][4];   // [cb][rt]
#pragma unroll
    for (int cb = 0; cb < 4; cb++)
#pragma unroll
        for (int rt = 0; rt < 4; rt++) acc[cb][rt] = (f32x4){0.f, 0.f, 0.f, 0.f};

#pragma unroll
    for (int ks = 0; ks < 4; ks++) {
        bf16x8 a[4];
#pragma unroll
        for (int rt = 0; rt < 4; rt++)
            a[rt] = *(const bf16x8*)(hs + (rt * 16 + llo) * HKPAD + ks * 32 + lhi * 8);
#pragma unroll
        for (int cb = 0; cb < 4; cb++) {
            bf16x8 b = *(const bf16x8*)(wbt + (size_t)(64 * wv + 16 * cb + llo) * 128 + ks * 32 + lhi * 8);
#pragma unroll
            for (int rt = 0; rt < 4; rt++)
                acc[cb][rt] = __builtin_amdgcn_mfma_f32_16x16x32_bf16(a[rt], b, acc[cb][rt], 0, 0, 0);
        }
    }

    float alv0 = al[64 * wv + llo],      alv1 = al[64 * wv + 16 + llo];
    float alv2 = al[64 * wv + 32 + llo], alv3 = al[64 * wv + 48 + llo];
    float arv0 = ar[64 * wv + llo],      arv1 = ar[64 * wv + 16 + llo];
    float arv2 = ar[64 * wv + 32 + llo], arv3 = ar[64 * wv + 48 + llo];

#pragma unroll
    for (int rt = 0; rt < 4; rt++) {
#pragma unroll
        for (int reg = 0; reg < 4; reg++) {
            int n = n0 + rt * 16 + lhi * 4 + reg;
            bool valid = (n < N);
            uint2 pv;
            pv.x = bf16pack(acc[0][rt][reg], acc[1][rt][reg]);
            pv.y = bf16pack(acc[2][rt][reg], acc[3][rt][reg]);
            if (valid) *((uint2*)(featb + (size_t)n * 256 + 64 * wv + 4 * llo)) = pv;
            float pl0 = acc[0][rt][reg] * alv0 + acc[1][rt][reg] * alv1;
            float pl1 = acc[2][rt][reg] * alv2 + acc[3][rt][reg] * alv3;
            float pr0 = acc[0][rt][reg] * arv0 + acc[1][rt][reg] * arv1;
            float pr1 = acc[2][rt][reg] * arv2 + acc[3][rt][reg] * arv3;
#pragma unroll
            for (int s = 1; s <= 8; s <<= 1) {
                pl0 += __shfl_xor(pl0, s, 64);
                pl1 += __shfl_xor(pl1, s, 64);
                pr0 += __shfl_xor(pr0, s, 64);
                pr1 += __shfl_xor(pr1, s, 64);
            }
            if (llo == 0 && valid) {
                *((float2*)(el + (size_t)n * 8 + 2 * wv)) = make_float2(pl0, pl1);
                *((float2*)(er + (size_t)n * 8 + 2 * wv)) = make_float2(pr0, pr1);
            }
        }
    }
}

// ---------- CSR build ----------
__global__ void hist_kernel(const int* __restrict__ edges, int* __restrict__ count, int E) {
    int e = blockIdx.x * blockDim.x + threadIdx.x;
    if (e < E) atomicAdd(&count[edges[E + e]], 1);
}

__global__ void scan1_kernel(const int* __restrict__ count, int* __restrict__ base,
                             int* __restrict__ bsum, int N) {
    __shared__ int wsum[4];
    int b = blockIdx.x;
    int i = b * 256 + threadIdx.x;
    int v = (i < N) ? count[i] : 0;
    int lane = threadIdx.x & 63;
    int wid = threadIdx.x >> 6;
    int x = v;
#pragma unroll
    for (int s = 1; s < 64; s <<= 1) {
        int y = __shfl_up(x, s, 64);
        if (lane >= s) x += y;
    }
    if (lane == 63) wsum[wid] = x;
    __syncthreads();
    int add = 0;
    for (int w = 0; w < wid; w++) add += wsum[w];
    int incl = x + add;
    if (i < N) base[i] = incl - v;
    if (threadIdx.x == 255) bsum[b] = incl;
}

__global__ void scan2_kernel(int* __restrict__ bsum, int nb) {
    __shared__ int wsum[4];
    int i = threadIdx.x;
    int v = (i < nb) ? bsum[i] : 0;
    int lane = threadIdx.x & 63;
    int wid = threadIdx.x >> 6;
    int x = v;
#pragma unroll
    for (int s = 1; s < 64; s <<= 1) {
        int y = __shfl_up(x, s, 64);
        if (lane >= s) x += y;
    }
    if (lane == 63) wsum[wid] = x;
    __syncthreads();
    int add = 0;
    for (int w = 0; w < wid; w++) add += wsum[w];
    if (i < nb) bsum[i] = x + add - v;
}

__global__ void scan3_kernel(int* __restrict__ base, const int* __restrict__ bsum, int N) {
    int i = blockIdx.x * blockDim.x + threadIdx.x;
    if (i < N) base[i] += bsum[i >> 8];
}

// scatter: pos = base[dst]+cursor++; store src and 8 pre-exponentiated logits
__global__ void scatter_kernel(const int* __restrict__ edges, const float* __restrict__ el,
                               const float* __restrict__ er, const int* __restrict__ base,
                               int* __restrict__ cursor, int* __restrict__ csr_src,
                               float* __restrict__ pedge, int E) {
    int e = blockIdx.x * blockDim.x + threadIdx.x;
    if (e >= E) return;
    int src = edges[e];
    int dst = edges[E + e];
    int pos = base[dst] + atomicAdd(&cursor[dst], 1);
    csr_src[pos] = src;
    float4 l0 = ((const float4*)el)[src * 2];
    float4 l1 = ((const float4*)el)[src * 2 + 1];
    float4 r0 = ((const float4*)er)[dst * 2];
    float4 r1 = ((const float4*)er)[dst * 2 + 1];
    float v[8] = {l0.x + r0.x, l0.y + r0.y, l0.z + r0.z, l0.w + r0.w,
                  l1.x + r1.x, l1.y + r1.y, l1.z + r1.z, l1.w + r1.w};
#pragma unroll
    for (int k = 0; k < 8; k++) {
        float t = (v[k] > 0.f) ? v[k] : NEG_SLOPE * v[k];
        v[k] = __expf(t);    // softmax is shift-invariant; logits are O(1)
    }
    ((float4*)pedge)[pos * 2]     = make_float4(v[0], v[1], v[2], v[3]);
    ((float4*)pedge)[pos * 2 + 1] = make_float4(v[4], v[5], v[6], v[7]);
}

// ---------- aggregate: one wave per dst, pure FMA inner loop, perm layout ----------
__global__ void aggregate_csr_kernel(const int* __restrict__ csr_src, const float* __restrict__ pedge,
                                     const int* __restrict__ base, const int* __restrict__ count,
                                     const ushort* __restrict__ featb, const float* __restrict__ bias,
                                     ushort* __restrict__ zb, int N) {
    int wid = threadIdx.x >> 6;
    int lane = threadIdx.x & 63;
    int dst = blockIdx.x * 4 + wid;
    if (dst >= N) return;
    int row0 = base[dst];
    int deg = count[dst];
    int w = lane >> 4, llo = lane & 15;
    int h0 = 2 * w;
    float d0 = 0.f, d1 = 0.f;
    float4 a = make_float4(0.f, 0.f, 0.f, 0.f);
    const float* pe = pedge + (size_t)row0 * 8;
    const int* cs = csr_src + row0;
    for (int t = 0; t < deg; t++) {
        float p0 = pe[(size_t)t * 8 + h0];
        float p1 = pe[(size_t)t * 8 + h0 + 1];
        int src = cs[t];
        uint2 u = ((const uint2*)featb)[(size_t)src * 64 + lane];
        d0 += p0; d1 += p1;
        a.x += p0 * bflo(u.x);
        a.y += p0 * bfhi(u.x);
        a.z += p1 * bflo(u.y);
        a.w += p1 * bfhi(u.y);
    }
    int c0 = 64 * w + llo;
    float b0 = bias[c0], b1 = bias[c0 + 16], b2 = bias[c0 + 32], b3 = bias[c0 + 48];
    float i0 = (d0 > 0.f) ? 1.f / d0 : 0.f;
    float i1 = (d1 > 0.f) ? 1.f / d1 : 0.f;
    uint2 o;
    o.x = bf16pack(a.x * i0 + b0, a.y * i0 + b1);
    o.y = bf16pack(a.z * i1 + b2, a.w * i1 + b3);
    ((uint2*)zb)[(size_t)dst * 64 + lane] = o;
}

// ---------- semantic attention via MFMA, B-reuse ----------
// 32 nodes/block (64 rows = node*2+mm), 4 waves. Wave w: col-tiles {2w,2w+1}, all 64 rows.
#define ZROW 264
__global__ void __launch_bounds__(256, 4)
semantic_kernel(const ushort* __restrict__ z0b, const ushort* __restrict__ z1b,
                const ushort* __restrict__ sw1t, const float* __restrict__ sb1,
                const float* __restrict__ sw2, float* __restrict__ wsum, int N) {
    __shared__ ushort zs[64 * ZROW];
    __shared__ float rowp[64];
    int n0 = blockIdx.x * 32;
    if (threadIdx.x < 64) rowp[threadIdx.x] = 0.f;
    for (int t = threadIdx.x; t < 64 * 32; t += 256) {
        int row = t >> 5, i16 = t & 31;
        int r = row >> 1, mm = row & 1;
        int n = n0 + r;
        uint4 v = make_uint4(0u, 0u, 0u, 0u);
        if (n < N) v = ((const uint4*)(mm ? z1b : z0b))[(size_t)n * 32 + i16];
        *((uint4*)(zs + row * ZROW + i16 * 8)) = v;
    }
    __syncthreads();

    int wv = threadIdx.x >> 6;
    int lane = threadIdx.x & 63;
    int lhi = lane >> 4, llo = lane & 15;

    f32x4 acc[2][4];   // [cbi][rt]
#pragma unroll
    for (int c = 0; c < 2; c++)
#pragma unroll
        for (int rt = 0; rt < 4; rt++) acc[c][rt] = (f32x4){0.f, 0.f, 0.f, 0.f};

#pragma unroll
    for (int ks = 0; ks < 8; ks++) {
        bf16x8 b0 = *(const bf16x8*)(sw1t + (size_t)((2 * wv) * 16 + llo) * 256 + ks * 32 + lhi * 8);
        bf16x8 b1 = *(const bf16x8*)(sw1t + (size_t)((2 * wv + 1) * 16 + llo) * 256 + ks * 32 + lhi * 8);
#pragma unroll
        for (int rt = 0; rt < 4; rt++) {
            bf16x8 av = *(const bf16x8*)(zs + (rt * 16 + llo) * ZROW + ks * 32 + lhi * 8);
            acc[0][rt] = __builtin_amdgcn_mfma_f32_16x16x32_bf16(av, b0, acc[0][rt], 0, 0, 0);
            acc[1][rt] = __builtin_amdgcn_mfma_f32_16x16x32_bf16(av, b1, acc[1][rt], 0, 0, 0);
        }
    }

    // epilogue: per row partial of tanh(acc+sb)*sw2 over this wave's 32 cols
    float sb0 = sb1[(2 * wv) * 16 + llo],     s20 = sw2[(2 * wv) * 16 + llo];
    float sb1v = sb1[(2 * wv + 1) * 16 + llo], s21 = sw2[(2 * wv + 1) * 16 + llo];
#pragma unroll
    for (int rt = 0; rt < 4; rt++) {
        float pr[4];
#pragma unroll
        for (int reg = 0; reg < 4; reg++)
            pr[reg] = tanhf(acc[0][rt][reg] + sb0) * s20 + tanhf(acc[1][rt][reg] + sb1v) * s21;
#pragma unroll
        for (int s = 1; s <= 8; s <<= 1)
#pragma unroll
            for (int reg = 0; reg < 4; reg++) pr[reg] += __shfl_xor(pr[reg], s, 64);
        if (llo == 0) {
#pragma unroll
            for (int reg = 0; reg < 4; reg++)
                atomicAdd(&rowp[rt * 16 + lhi * 4 + reg], pr[reg]);
        }
    }
    __syncthreads();
    if (threadIdx.x < 64) {
        int node = n0 + (threadIdx.x >> 1);
        float v = (node < N) ? rowp[threadIdx.x] : 0.f;
        v += __shfl_xor(v, 2, 64);
        v += __shfl_xor(v, 4, 64);
        v += __shfl_xor(v, 8, 64);
        v += __shfl_xor(v, 16, 64);
        v += __shfl_xor(v, 32, 64);
        if (threadIdx.x < 2) atomicAdd(&wsum[threadIdx.x], v);
    }
}

// ---------- beta = softmax(wsum/N) ----------
__global__ void beta_kernel(const float* __restrict__ wsum, float* __restrict__ beta, float invN) {
    if (threadIdx.x == 0 && blockIdx.x == 0) {
        float w0 = wsum[0] * invN, w1 = wsum[1] * invN;
        float mx = fmaxf(w0, w1);
        float e0 = expf(w0 - mx), e1 = expf(w1 - mx);
        float s = e0 + e1;
        beta[0] = e0 / s;
        beta[1] = e1 / s;
    }
}

// ---------- out(f32, unpermuted) = beta0*z0b + beta1*z1b ----------
__global__ void combine_kernel(float* __restrict__ out, const ushort* __restrict__ z0b,
                               const ushort* __restrict__ z1b, const float* __restrict__ beta,
                               int N) {
    int idx = blockIdx.x * 256 + threadIdx.x;
    if (idx >= N * 64) return;
    int n = idx >> 6, lane = idx & 63;
    int w = lane >> 4, llo = lane & 15;
    float b0 = beta[0], b1 = beta[1];
    uint2 a = ((const uint2*)z0b)[idx];
    uint2 b = ((const uint2*)z1b)[idx];
    float* o = out + (size_t)n * 256 + 64 * w + llo;
    o[0]  = b0 * bflo(a.x) + b1 * bflo(b.x);
    o[16] = b0 * bfhi(a.x) + b1 * bfhi(b.x);
    o[32] = b0 * bflo(a.y) + b1 * bflo(b.y);
    o[48] = b0 * bfhi(a.y) + b1 * bfhi(b.y);
}

extern "C" void kernel_launch(void* const* d_in, const int* in_sizes, int n_in,
                              void* d_out, int out_size, void* d_ws, size_t ws_size,
                              hipStream_t stream) {
    const float* h      = (const float*)d_in[0];
    const int*   edges0 = (const int*)d_in[1];
    const int*   edges1 = (const int*)d_in[2];
    const float* fc0    = (const float*)d_in[3];
    const float* al0    = (const float*)d_in[4];
    const float* ar0    = (const float*)d_in[5];
    const float* bias0  = (const float*)d_in[6];
    const float* fc1    = (const float*)d_in[7];
    const float* al1    = (const float*)d_in[8];
    const float* ar1    = (const float*)d_in[9];
    const float* bias1  = (const float*)d_in[10];
    const float* bias_unused = bias1; (void)bias_unused;
    const float* sw1    = (const float*)d_in[11];
    const float* sb1    = (const float*)d_in[12];
    const float* sw2    = (const float*)d_in[13];

    const int N = in_sizes[0] / 128;
    const int E = in_sizes[1] / 2;
    const int NB = (N + 255) / 256;

    char* ws = (char*)d_ws;
    ushort* featb = (ushort*)ws;                       // N*256 bf16 (perm layout)
    ushort* z0b   = featb + (size_t)N * 256;           // N*256
    ushort* z1b   = z0b + (size_t)N * 256;             // N*256
    ushort* hb    = z1b + (size_t)N * 256;             // N*128
    ushort* wbt   = hb + (size_t)N * 128;              // 2*256*128
    ushort* sw1t  = wbt + 2 * 256 * 128;               // 128*256
    float*  el    = (float*)(sw1t + 128 * 256);        // N*8
    float*  er    = el + (size_t)N * 8;                // N*8
    float*  pedge = er + (size_t)N * 8;                // E*8
    int*    csr_src = (int*)(pedge + (size_t)E * 8);   // E
    int*    count   = csr_src + E;                     // N
    int*    base    = count + N;                       // N
    int*    cursor  = base + N;                        // N
    int*    bsum    = cursor + N;                      // NB
    float*  wsum  = (float*)(bsum + NB + 2);           // 2
    float*  beta  = wsum + 2;                          // 2
    float*  outp  = (float*)d_out;                     // N*256 f32

    hb_kernel<<<(N * 16 + 255) / 256, 256, 0, stream>>>(h, hb, wsum, N * 16);
    wbt_kernel<<<256, 256, 0, stream>>>(fc0, fc1, wbt);
    sw1t_kernel<<<128, 256, 0, stream>>>(sw1, sw1t);

    for (int l = 0; l < 2; l++) {
        const float* alp  = l ? al1 : al0;
        const float* arp  = l ? ar1 : ar0;
        const float* bias = l ? bias1 : bias0;
        const int*  edges = l ? edges1 : edges0;
        ushort* zb = l ? z1b : z0b;

        zero_counts_kernel<<<NB, 256, 0, stream>>>(count, cursor, N);
        fc_kernel<<<(N + 63) / 64, 256, 0, stream>>>(hb, wbt + l * 32768, alp, arp,
                                                     featb, el, er, N);
        hist_kernel<<<(E + 255) / 256, 256, 0, stream>>>(edges, count, E);
        scan1_kernel<<<NB, 256, 0, stream>>>(count, base, bsum, N);
        scan2_kernel<<<1, 256, 0, stream>>>(bsum, NB);
        scan3_kernel<<<NB, 256, 0, stream>>>(base, bsum, N);
        scatter_kernel<<<(E + 255) / 256, 256, 0, stream>>>(edges, el, er, base, cursor,
                                                            csr_src, pedge, E);
        aggregate_csr_kernel<<<(N + 3) / 4, 256, 0, stream>>>(csr_src, pedge, base, count,
                                                              featb, bias, zb, N);
    }

    semantic_kernel<<<(N + 31) / 32, 256, 0, stream>>>(z0b, z1b, sw1t, sb1, sw2, wsum, N);
    beta_kernel<<<1, 64, 0, stream>>>(wsum, beta, 1.0f / (float)N);
    combine_kernel<<<(N * 64 + 255) / 256, 256, 0, stream>>>(outp, z0b, z1b, beta, N);
}

// Round 7
// 264.916 us; speedup vs baseline: 2.1322x; 1.2792x over previous
//
#include <hip/hip_runtime.h>
#include <math.h>

#define NEG_SLOPE 0.2f

typedef unsigned int uint;
typedef unsigned short ushort;
typedef __bf16 bf16x8 __attribute__((ext_vector_type(8)));
typedef float f32x4 __attribute__((ext_vector_type(4)));

__device__ __forceinline__ uint bf16r(float a) {
    uint u = __float_as_uint(a);
    return (u + 0x7fffu + ((u >> 16) & 1u)) >> 16;
}
__device__ __forceinline__ uint bf16pack(float a, float b) {
    return bf16r(a) | (bf16r(b) << 16);
}
__device__ __forceinline__ float bflo(uint u) { return __uint_as_float(u << 16); }
__device__ __forceinline__ float bfhi(uint u) { return __uint_as_float(u & 0xffff0000u); }

// ---------- prep: wbt (both W transposed bf16), sw1t (perm), wsum=0 ----------
__global__ void prep_kernel(const float* __restrict__ fc0, const float* __restrict__ fc1,
                            const float* __restrict__ sw1, ushort* __restrict__ wbt,
                            ushort* __restrict__ sw1t, float* __restrict__ wsum) {
    int b = blockIdx.x;
    if (b == 0 && threadIdx.x == 0) { wsum[0] = 0.f; wsum[1] = 0.f; }
    if (b < 256) {
        int idx = b * 256 + threadIdx.x;            // 65536
        const float* W = (idx >> 15) ? fc1 : fc0;
        int r = idx & 32767;
        int c = r >> 7, k = r & 127;
        wbt[idx] = (ushort)bf16r(W[(size_t)k * 256 + c]);
    } else {
        int idx = (b - 256) * 256 + threadIdx.x;    // 32768
        int c = idx >> 8, p = idx & 255;
        int col = (p & ~63) + ((p & 3) * 16) + ((p >> 2) & 15);
        sw1t[idx] = (ushort)bf16r(sw1[(size_t)col * 128 + c]);
    }
}

__global__ void zero_counts_kernel(int* __restrict__ count, int* __restrict__ cursor, int Ntot) {
    int i = blockIdx.x * blockDim.x + threadIdx.x;
    if (i < Ntot) { count[i] = 0; cursor[i] = 0; }
}

// ---------- hist over both layers: d' = dst + l*N ----------
__global__ void hist_kernel(const int* __restrict__ e0, const int* __restrict__ e1,
                            int* __restrict__ count, int E, int N) {
    int e = blockIdx.x * blockDim.x + threadIdx.x;
    if (e >= 2 * E) return;
    int l = (e >= E);
    int ee = e - l * E;
    const int* edges = l ? e1 : e0;
    atomicAdd(&count[edges[E + ee] + l * N], 1);
}

__global__ void scan1_kernel(const int* __restrict__ count, int* __restrict__ base,
                             int* __restrict__ bsum, int Ntot) {
    __shared__ int ws_s[4];
    int b = blockIdx.x;
    int i = b * 256 + threadIdx.x;
    int v = (i < Ntot) ? count[i] : 0;
    int lane = threadIdx.x & 63;
    int wid = threadIdx.x >> 6;
    int x = v;
#pragma unroll
    for (int s = 1; s < 64; s <<= 1) {
        int y = __shfl_up(x, s, 64);
        if (lane >= s) x += y;
    }
    if (lane == 63) ws_s[wid] = x;
    __syncthreads();
    int add = 0;
    for (int w = 0; w < wid; w++) add += ws_s[w];
    int incl = x + add;
    if (i < Ntot) base[i] = incl - v;
    if (threadIdx.x == 255) bsum[b] = incl;
}

// chunked single-block exclusive scan (any nb)
__global__ void scan2_kernel(int* __restrict__ bsum, int nb) {
    __shared__ int ws_s[4];
    __shared__ int running_s;
    if (threadIdx.x == 0) running_s = 0;
    __syncthreads();
    int lane = threadIdx.x & 63;
    int wid = threadIdx.x >> 6;
    for (int c0 = 0; c0 < nb; c0 += 256) {
        int i = c0 + threadIdx.x;
        int v = (i < nb) ? bsum[i] : 0;
        int x = v;
#pragma unroll
        for (int s = 1; s < 64; s <<= 1) {
            int y = __shfl_up(x, s, 64);
            if (lane >= s) x += y;
        }
        if (lane == 63) ws_s[wid] = x;
        __syncthreads();
        int add = 0;
        for (int w = 0; w < wid; w++) add += ws_s[w];
        int incl = x + add;
        int run = running_s;
        if (i < nb) bsum[i] = run + incl - v;
        __syncthreads();
        if (threadIdx.x == 255) running_s = run + incl;
        __syncthreads();
    }
}

// ---------- fc via MFMA, both layers in one grid ----------
// block b: layer l = b>=nb, nodes n0 = (b-l*nb)*64. 4 waves; wave wv: cols 64wv..64wv+63.
// featb layout per layer: featb[l*N*256 + n*256 + p], p = 64wv + 4*llo + cb  (col = 64wv+16cb+llo)
#define HKPAD 136
__global__ void __launch_bounds__(256, 4)
fc_kernel(const float* __restrict__ h, const ushort* __restrict__ wbt,
          const float* __restrict__ al0, const float* __restrict__ ar0,
          const float* __restrict__ al1, const float* __restrict__ ar1,
          ushort* __restrict__ featb, float* __restrict__ el,
          float* __restrict__ er, int N, int nb) {
    __shared__ ushort hs[64 * HKPAD];
    int b = blockIdx.x;
    int l = (b >= nb);
    int n0 = (b - l * nb) * 64;
    for (int t = threadIdx.x; t < 64 * 32; t += 256) {
        int r = t >> 5, i4 = t & 31;
        int n = n0 + r;
        float4 v = make_float4(0.f, 0.f, 0.f, 0.f);
        if (n < N) v = ((const float4*)h)[(size_t)n * 32 + i4];
        uint2 pk;
        pk.x = bf16pack(v.x, v.y);
        pk.y = bf16pack(v.z, v.w);
        *((uint2*)(hs + r * HKPAD + i4 * 4)) = pk;
    }
    __syncthreads();

    const ushort* wb = wbt + l * 32768;
    const float* al = l ? al1 : al0;
    const float* ar = l ? ar1 : ar0;
    ushort* fb = featb + (size_t)l * N * 256;
    float* elp = el + (size_t)l * N * 8;
    float* erp = er + (size_t)l * N * 8;

    int wv = threadIdx.x >> 6;
    int lane = threadIdx.x & 63;
    int lhi = lane >> 4, llo = lane & 15;

    f32x4 acc[4][4];   // [cb][rt]
#pragma unroll
    for (int cb = 0; cb < 4; cb++)
#pragma unroll
        for (int rt = 0; rt < 4; rt++) acc[cb][rt] = (f32x4){0.f, 0.f, 0.f, 0.f};

#pragma unroll
    for (int ks = 0; ks < 4; ks++) {
        bf16x8 a[4];
#pragma unroll
        for (int rt = 0; rt < 4; rt++)
            a[rt] = *(const bf16x8*)(hs + (rt * 16 + llo) * HKPAD + ks * 32 + lhi * 8);
#pragma unroll
        for (int cb = 0; cb < 4; cb++) {
            bf16x8 bfrag = *(const bf16x8*)(wb + (size_t)(64 * wv + 16 * cb + llo) * 128 + ks * 32 + lhi * 8);
#pragma unroll
            for (int rt = 0; rt < 4; rt++)
                acc[cb][rt] = __builtin_amdgcn_mfma_f32_16x16x32_bf16(a[rt], bfrag, acc[cb][rt], 0, 0, 0);
        }
    }

    float alv0 = al[64 * wv + llo],      alv1 = al[64 * wv + 16 + llo];
    float alv2 = al[64 * wv + 32 + llo], alv3 = al[64 * wv + 48 + llo];
    float arv0 = ar[64 * wv + llo],      arv1 = ar[64 * wv + 16 + llo];
    float arv2 = ar[64 * wv + 32 + llo], arv3 = ar[64 * wv + 48 + llo];

#pragma unroll
    for (int rt = 0; rt < 4; rt++) {
#pragma unroll
        for (int reg = 0; reg < 4; reg++) {
            int n = n0 + rt * 16 + lhi * 4 + reg;
            bool valid = (n < N);
            uint2 pv;
            pv.x = bf16pack(acc[0][rt][reg], acc[1][rt][reg]);
            pv.y = bf16pack(acc[2][rt][reg], acc[3][rt][reg]);
            if (valid) *((uint2*)(fb + (size_t)n * 256 + 64 * wv + 4 * llo)) = pv;
            float pl0 = acc[0][rt][reg] * alv0 + acc[1][rt][reg] * alv1;
            float pl1 = acc[2][rt][reg] * alv2 + acc[3][rt][reg] * alv3;
            float pr0 = acc[0][rt][reg] * arv0 + acc[1][rt][reg] * arv1;
            float pr1 = acc[2][rt][reg] * arv2 + acc[3][rt][reg] * arv3;
#pragma unroll
            for (int s = 1; s <= 8; s <<= 1) {
                pl0 += __shfl_xor(pl0, s, 64);
                pl1 += __shfl_xor(pl1, s, 64);
                pr0 += __shfl_xor(pr0, s, 64);
                pr1 += __shfl_xor(pr1, s, 64);
            }
            if (llo == 0 && valid) {
                *((float2*)(elp + (size_t)n * 8 + 2 * wv)) = make_float2(pl0, pl1);
                *((float2*)(erp + (size_t)n * 8 + 2 * wv)) = make_float2(pr0, pr1);
            }
        }
    }
}

// ---------- scatter over both layers: pos = base[d']+bsum+cursor++ ----------
__global__ void scatter_kernel(const int* __restrict__ e0, const int* __restrict__ e1,
                               const float* __restrict__ el, const float* __restrict__ er,
                               const int* __restrict__ base, const int* __restrict__ bsum,
                               int* __restrict__ cursor, int* __restrict__ csr_src,
                               float* __restrict__ pedge, int E, int N) {
    int e = blockIdx.x * blockDim.x + threadIdx.x;
    if (e >= 2 * E) return;
    int l = (e >= E);
    int ee = e - l * E;
    const int* edges = l ? e1 : e0;
    int src = edges[ee];
    int dst = edges[E + ee];
    int d = dst + l * N;
    int pos = base[d] + bsum[d >> 8] + atomicAdd(&cursor[d], 1);
    csr_src[pos] = src;
    size_t so = (size_t)(l * N + src) * 2;
    size_t dofs = (size_t)(l * N + dst) * 2;
    float4 l0 = ((const float4*)el)[so];
    float4 l1 = ((const float4*)el)[so + 1];
    float4 r0 = ((const float4*)er)[dofs];
    float4 r1 = ((const float4*)er)[dofs + 1];
    float v[8] = {l0.x + r0.x, l0.y + r0.y, l0.z + r0.z, l0.w + r0.w,
                  l1.x + r1.x, l1.y + r1.y, l1.z + r1.z, l1.w + r1.w};
#pragma unroll
    for (int k = 0; k < 8; k++) {
        float t = (v[k] > 0.f) ? v[k] : NEG_SLOPE * v[k];
        v[k] = __expf(t);    // softmax shift-invariant; logits O(1)
    }
    ((float4*)pedge)[pos * 2]     = make_float4(v[0], v[1], v[2], v[3]);
    ((float4*)pedge)[pos * 2 + 1] = make_float4(v[4], v[5], v[6], v[7]);
}

// ---------- aggregate both layers: one wave per d', 4-wide unrolled gathers ----------
__global__ void aggregate_csr_kernel(const int* __restrict__ csr_src, const float* __restrict__ pedge,
                                     const int* __restrict__ base, const int* __restrict__ bsum,
                                     const int* __restrict__ count, const ushort* __restrict__ featb,
                                     const float* __restrict__ bias0, const float* __restrict__ bias1,
                                     ushort* __restrict__ z0b, ushort* __restrict__ z1b, int N) {
    int wid = threadIdx.x >> 6;
    int lane = threadIdx.x & 63;
    int d = blockIdx.x * 4 + wid;
    if (d >= 2 * N) return;
    int l = (d >= N);
    int dst = d - l * N;
    int row0 = base[d] + bsum[d >> 8];
    int deg = count[d];
    int w = lane >> 4, llo = lane & 15;
    const ushort* fb = featb + (size_t)l * N * 256;
    const float2* pe = (const float2*)(pedge + (size_t)row0 * 8);
    const int* cs = csr_src + row0;
    const uint2* fb2 = (const uint2*)fb;

    float d0 = 0.f, d1 = 0.f;
    float4 a = make_float4(0.f, 0.f, 0.f, 0.f);
    int t = 0;
    for (; t + 4 <= deg; t += 4) {
        int s0 = cs[t], s1 = cs[t + 1], s2 = cs[t + 2], s3 = cs[t + 3];
        float2 q0 = pe[t * 4 + w];
        float2 q1 = pe[t * 4 + 4 + w];
        float2 q2 = pe[t * 4 + 8 + w];
        float2 q3 = pe[t * 4 + 12 + w];
        uint2 u0 = fb2[(size_t)s0 * 64 + lane];
        uint2 u1 = fb2[(size_t)s1 * 64 + lane];
        uint2 u2 = fb2[(size_t)s2 * 64 + lane];
        uint2 u3 = fb2[(size_t)s3 * 64 + lane];
        d0 += q0.x; d1 += q0.y;
        a.x += q0.x * bflo(u0.x); a.y += q0.x * bfhi(u0.x);
        a.z += q0.y * bflo(u0.y); a.w += q0.y * bfhi(u0.y);
        d0 += q1.x; d1 += q1.y;
        a.x += q1.x * bflo(u1.x); a.y += q1.x * bfhi(u1.x);
        a.z += q1.y * bflo(u1.y); a.w += q1.y * bfhi(u1.y);
        d0 += q2.x; d1 += q2.y;
        a.x += q2.x * bflo(u2.x); a.y += q2.x * bfhi(u2.x);
        a.z += q2.y * bflo(u2.y); a.w += q2.y * bfhi(u2.y);
        d0 += q3.x; d1 += q3.y;
        a.x += q3.x * bflo(u3.x); a.y += q3.x * bfhi(u3.x);
        a.z += q3.y * bflo(u3.y); a.w += q3.y * bfhi(u3.y);
    }
    for (; t < deg; t++) {
        int s0 = cs[t];
        float2 q0 = pe[t * 4 + w];
        uint2 u0 = fb2[(size_t)s0 * 64 + lane];
        d0 += q0.x; d1 += q0.y;
        a.x += q0.x * bflo(u0.x); a.y += q0.x * bfhi(u0.x);
        a.z += q0.y * bflo(u0.y); a.w += q0.y * bfhi(u0.y);
    }
    const float* bias = l ? bias1 : bias0;
    int c0 = 64 * w + llo;
    float b0 = bias[c0], b1 = bias[c0 + 16], b2 = bias[c0 + 32], b3 = bias[c0 + 48];
    float i0 = (d0 > 0.f) ? 1.f / d0 : 0.f;
    float i1 = (d1 > 0.f) ? 1.f / d1 : 0.f;
    uint2 o;
    o.x = bf16pack(a.x * i0 + b0, a.y * i0 + b1);
    o.y = bf16pack(a.z * i1 + b2, a.w * i1 + b3);
    ushort* zb = l ? z1b : z0b;
    ((uint2*)zb)[(size_t)dst * 64 + lane] = o;
}

// ---------- semantic attention via MFMA, B-reuse ----------
#define ZROW 264
__global__ void __launch_bounds__(256, 4)
semantic_kernel(const ushort* __restrict__ z0b, const ushort* __restrict__ z1b,
                const ushort* __restrict__ sw1t, const float* __restrict__ sb1,
                const float* __restrict__ sw2, float* __restrict__ wsum, int N) {
    __shared__ ushort zs[64 * ZROW];
    __shared__ float rowp[64];
    int n0 = blockIdx.x * 32;
    if (threadIdx.x < 64) rowp[threadIdx.x] = 0.f;
    for (int t = threadIdx.x; t < 64 * 32; t += 256) {
        int row = t >> 5, i16 = t & 31;
        int r = row >> 1, mm = row & 1;
        int n = n0 + r;
        uint4 v = make_uint4(0u, 0u, 0u, 0u);
        if (n < N) v = ((const uint4*)(mm ? z1b : z0b))[(size_t)n * 32 + i16];
        *((uint4*)(zs + row * ZROW + i16 * 8)) = v;
    }
    __syncthreads();

    int wv = threadIdx.x >> 6;
    int lane = threadIdx.x & 63;
    int lhi = lane >> 4, llo = lane & 15;

    f32x4 acc[2][4];
#pragma unroll
    for (int c = 0; c < 2; c++)
#pragma unroll
        for (int rt = 0; rt < 4; rt++) acc[c][rt] = (f32x4){0.f, 0.f, 0.f, 0.f};

#pragma unroll
    for (int ks = 0; ks < 8; ks++) {
        bf16x8 b0 = *(const bf16x8*)(sw1t + (size_t)((2 * wv) * 16 + llo) * 256 + ks * 32 + lhi * 8);
        bf16x8 b1 = *(const bf16x8*)(sw1t + (size_t)((2 * wv + 1) * 16 + llo) * 256 + ks * 32 + lhi * 8);
#pragma unroll
        for (int rt = 0; rt < 4; rt++) {
            bf16x8 av = *(const bf16x8*)(zs + (rt * 16 + llo) * ZROW + ks * 32 + lhi * 8);
            acc[0][rt] = __builtin_amdgcn_mfma_f32_16x16x32_bf16(av, b0, acc[0][rt], 0, 0, 0);
            acc[1][rt] = __builtin_amdgcn_mfma_f32_16x16x32_bf16(av, b1, acc[1][rt], 0, 0, 0);
        }
    }

    float sb0 = sb1[(2 * wv) * 16 + llo],      s20 = sw2[(2 * wv) * 16 + llo];
    float sb1v = sb1[(2 * wv + 1) * 16 + llo], s21 = sw2[(2 * wv + 1) * 16 + llo];
#pragma unroll
    for (int rt = 0; rt < 4; rt++) {
        float pr[4];
#pragma unroll
        for (int reg = 0; reg < 4; reg++)
            pr[reg] = tanhf(acc[0][rt][reg] + sb0) * s20 + tanhf(acc[1][rt][reg] + sb1v) * s21;
#pragma unroll
        for (int s = 1; s <= 8; s <<= 1)
#pragma unroll
            for (int reg = 0; reg < 4; reg++) pr[reg] += __shfl_xor(pr[reg], s, 64);
        if (llo == 0) {
#pragma unroll
            for (int reg = 0; reg < 4; reg++)
                atomicAdd(&rowp[rt * 16 + lhi * 4 + reg], pr[reg]);
        }
    }
    __syncthreads();
    if (threadIdx.x < 64) {
        int node = n0 + (threadIdx.x >> 1);
        float v = (node < N) ? rowp[threadIdx.x] : 0.f;
        v += __shfl_xor(v, 2, 64);
        v += __shfl_xor(v, 4, 64);
        v += __shfl_xor(v, 8, 64);
        v += __shfl_xor(v, 16, 64);
        v += __shfl_xor(v, 32, 64);
        if (threadIdx.x < 2) atomicAdd(&wsum[threadIdx.x], v);
    }
}

// ---------- beta = softmax(wsum/N) ----------
__global__ void beta_kernel(const float* __restrict__ wsum, float* __restrict__ beta, float invN) {
    if (threadIdx.x == 0 && blockIdx.x == 0) {
        float w0 = wsum[0] * invN, w1 = wsum[1] * invN;
        float mx = fmaxf(w0, w1);
        float e0 = expf(w0 - mx), e1 = expf(w1 - mx);
        float s = e0 + e1;
        beta[0] = e0 / s;
        beta[1] = e1 / s;
    }
}

// ---------- out(f32, unpermuted) = beta0*z0b + beta1*z1b ----------
__global__ void combine_kernel(float* __restrict__ out, const ushort* __restrict__ z0b,
                               const ushort* __restrict__ z1b, const float* __restrict__ beta,
                               int N) {
    int idx = blockIdx.x * 256 + threadIdx.x;
    if (idx >= N * 64) return;
    int n = idx >> 6, lane = idx & 63;
    int w = lane >> 4, llo = lane & 15;
    float b0 = beta[0], b1 = beta[1];
    uint2 a = ((const uint2*)z0b)[idx];
    uint2 b = ((const uint2*)z1b)[idx];
    float* o = out + (size_t)n * 256 + 64 * w + llo;
    o[0]  = b0 * bflo(a.x) + b1 * bflo(b.x);
    o[16] = b0 * bfhi(a.x) + b1 * bfhi(b.x);
    o[32] = b0 * bflo(a.y) + b1 * bflo(b.y);
    o[48] = b0 * bfhi(a.y) + b1 * bfhi(b.y);
}

extern "C" void kernel_launch(void* const* d_in, const int* in_sizes, int n_in,
                              void* d_out, int out_size, void* d_ws, size_t ws_size,
                              hipStream_t stream) {
    const float* h      = (const float*)d_in[0];
    const int*   edges0 = (const int*)d_in[1];
    const int*   edges1 = (const int*)d_in[2];
    const float* fc0    = (const float*)d_in[3];
    const float* al0    = (const float*)d_in[4];
    const float* ar0    = (const float*)d_in[5];
    const float* bias0  = (const float*)d_in[6];
    const float* fc1    = (const float*)d_in[7];
    const float* al1    = (const float*)d_in[8];
    const float* ar1    = (const float*)d_in[9];
    const float* bias1  = (const float*)d_in[10];
    const float* sw1    = (const float*)d_in[11];
    const float* sb1    = (const float*)d_in[12];
    const float* sw2    = (const float*)d_in[13];

    const int N = in_sizes[0] / 128;
    const int E = in_sizes[1] / 2;
    const int Ntot = 2 * N;
    const int NB2 = (Ntot + 255) / 256;
    const int nb = (N + 63) / 64;

    char* ws = (char*)d_ws;
    ushort* featb = (ushort*)ws;                       // 2N*256 bf16 (perm, per layer)
    ushort* z0b   = featb + (size_t)Ntot * 256;        // N*256
    ushort* z1b   = z0b + (size_t)N * 256;             // N*256
    ushort* wbt   = z1b + (size_t)N * 256;             // 2*256*128
    ushort* sw1t  = wbt + 2 * 256 * 128;               // 128*256
    float*  el    = (float*)(sw1t + 128 * 256);        // 2N*8
    float*  er    = el + (size_t)Ntot * 8;             // 2N*8
    float*  pedge = er + (size_t)Ntot * 8;             // 2E*8
    int*    csr_src = (int*)(pedge + (size_t)E * 16);  // 2E
    int*    count   = csr_src + 2 * E;                 // 2N
    int*    base    = count + Ntot;                    // 2N
    int*    cursor  = base + Ntot;                     // 2N
    int*    bsum    = cursor + Ntot;                   // NB2
    float*  wsum  = (float*)(bsum + NB2 + 2);          // 2
    float*  beta  = wsum + 2;                          // 2
    float*  outp  = (float*)d_out;                     // N*256 f32

    prep_kernel<<<384, 256, 0, stream>>>(fc0, fc1, sw1, wbt, sw1t, wsum);
    zero_counts_kernel<<<NB2, 256, 0, stream>>>(count, cursor, Ntot);
    hist_kernel<<<(2 * E + 255) / 256, 256, 0, stream>>>(edges0, edges1, count, E, N);
    scan1_kernel<<<NB2, 256, 0, stream>>>(count, base, bsum, Ntot);
    scan2_kernel<<<1, 256, 0, stream>>>(bsum, NB2);
    fc_kernel<<<2 * nb, 256, 0, stream>>>(h, wbt, al0, ar0, al1, ar1, featb, el, er, N, nb);
    scatter_kernel<<<(2 * E + 255) / 256, 256, 0, stream>>>(edges0, edges1, el, er, base, bsum,
                                                            cursor, csr_src, pedge, E, N);
    aggregate_csr_kernel<<<(Ntot + 3) / 4, 256, 0, stream>>>(csr_src, pedge, base, bsum, count,
                                                             featb, bias0, bias1, z0b, z1b, N);
    semantic_kernel<<<(N + 31) / 32, 256, 0, stream>>>(z0b, z1b, sw1t, sb1, sw2, wsum, N);
    beta_kernel<<<1, 64, 0, stream>>>(wsum, beta, 1.0f / (float)N);
    combine_kernel<<<(N * 64 + 255) / 256, 256, 0, stream>>>(outp, z0b, z1b, beta, N);
}